// Round 1
// baseline (97.781 us; speedup 1.0000x reference)
//
#include <hip/hip_runtime.h>
#include <math.h>

// S4D SSM kernel materialization:
//   K[h,l] = 2 * Re( sum_n CB[h,n] * exp(dtA[h,n] * l) ) + D[h]*(l==0)
// where dtA = exp(log_dt[h]) * Lambda[h,n],
//       CB  = C[h,n] * (expm1(dtA)/Lambda[h,n]) * B[h,n]
// H=1024, N=64, L=1024 (all derived from sizes at launch).

#define NSTATE 64

__global__ __launch_bounds__(256) void ssk_diag_kernel(
    const float* __restrict__ log_dt,   // (H,)
    const float* __restrict__ Lre,      // (H,N)
    const float* __restrict__ Lim,      // (H,N)
    const float* __restrict__ Bv,       // (H,N,1)
    const float* __restrict__ Cre,      // (H,1,N)
    const float* __restrict__ Cim,      // (H,1,N)
    const float* __restrict__ Dv,       // (H,)
    float* __restrict__ K,              // (H,L)
    int L)
{
    const int h   = blockIdx.x;
    const int tid = threadIdx.x;

    __shared__ float s_are[NSTATE];   // Re(dtA)
    __shared__ float s_aim[NSTATE];   // Im(dtA)
    __shared__ float s_cbre[NSTATE];  // Re(CB)
    __shared__ float s_cbim[NSTATE];  // Im(CB)

    if (tid < NSTATE) {
        const int n   = tid;
        const int idx = h * NSTATE + n;
        const float dt  = expf(log_dt[h]);
        const float lre = Lre[idx];
        const float lim = Lim[idx];
        const float are = dt * lre;
        const float aim = dt * lim;

        // Stable complex expm1: exp(are+i*aim) - 1
        //   re = expm1(are)*cos(aim) - 2*sin^2(aim/2)
        //   im = exp(are)*sin(aim)
        float sy, cy;
        sincosf(aim, &sy, &cy);
        const float sh    = sinf(0.5f * aim);
        const float em_re = expm1f(are) * cy - 2.0f * sh * sh;
        const float em_im = expf(are) * sy;

        // B_bar = em / Lambda * B  =  em * conj(Lambda) / |Lambda|^2 * B
        const float inv_d = 1.0f / (lre * lre + lim * lim);
        const float b     = Bv[idx];
        const float bb_re = (em_re * lre + em_im * lim) * inv_d * b;
        const float bb_im = (em_im * lre - em_re * lim) * inv_d * b;

        // CB = (Cre + i*Cim) * B_bar
        const float cre = Cre[idx];
        const float cim = Cim[idx];
        s_cbre[n] = cre * bb_re - cim * bb_im;
        s_cbim[n] = cre * bb_im + cim * bb_re;
        s_are[n]  = are;
        s_aim[n]  = aim;
    }
    __syncthreads();

    const float Dh = Dv[h];
    for (int l = tid; l < L; l += blockDim.x) {
        const float fl = (float)l;
        // two accumulators to shorten the fma dependency chain
        float acc0 = 0.0f, acc1 = 0.0f;
        #pragma unroll
        for (int n = 0; n < NSTATE; n += 2) {
            {
                const float mag = __expf(s_are[n] * fl);
                float s, c;
                __sincosf(s_aim[n] * fl, &s, &c);
                acc0 += mag * (s_cbre[n] * c - s_cbim[n] * s);
            }
            {
                const float mag = __expf(s_are[n + 1] * fl);
                float s, c;
                __sincosf(s_aim[n + 1] * fl, &s, &c);
                acc1 += mag * (s_cbre[n + 1] * c - s_cbim[n + 1] * s);
            }
        }
        float acc = 2.0f * (acc0 + acc1);
        if (l == 0) acc += Dh;
        K[h * L + l] = acc;
    }
}

extern "C" void kernel_launch(void* const* d_in, const int* in_sizes, int n_in,
                              void* d_out, int out_size, void* d_ws, size_t ws_size,
                              hipStream_t stream) {
    const float* log_dt = (const float*)d_in[0];
    const float* Lre    = (const float*)d_in[1];
    const float* Lim    = (const float*)d_in[2];
    const float* B      = (const float*)d_in[3];
    const float* Cre    = (const float*)d_in[4];
    const float* Cim    = (const float*)d_in[5];
    const float* D      = (const float*)d_in[6];
    // d_in[7] is L as a device scalar; derive sizes host-side instead.
    const int H = in_sizes[0];
    const int L = out_size / H;
    float* K = (float*)d_out;

    ssk_diag_kernel<<<H, 256, 0, stream>>>(log_dt, Lre, Lim, B, Cre, Cim, D, K, L);
}

// Round 2
// 83.799 us; speedup vs baseline: 1.1669x; 1.1669x over previous
//
#include <hip/hip_runtime.h>
#include <math.h>

// S4D SSM kernel materialization:
//   K[h,l] = 2 * Re( sum_n CB[h,n] * exp(dtA[h,n] * l) ) + D[h]*(l==0)
// where dtA = exp(log_dt[h]) * Lambda[h,n],
//       CB  = C[h,n] * (expm1(dtA)/Lambda[h,n]) * B[h,n]
//
// R2 strategy: per-thread chunk of T=4 consecutive l. One trans-evaluation of
// z0 = exp(dtA*l0) per (n, chunk); then w = CB*z0 rotated by step=exp(dtA)
// (complex mul recurrence, no transcendentals). Cuts trans ops 4x and removes
// large-argument sincos from the inner loop.

#define NSTATE 64
#define TCHUNK 4

__global__ __launch_bounds__(256) void ssk_diag_kernel(
    const float* __restrict__ log_dt,   // (H,)
    const float* __restrict__ Lre,      // (H,N)
    const float* __restrict__ Lim,      // (H,N)
    const float* __restrict__ Bv,       // (H,N,1)
    const float* __restrict__ Cre,      // (H,1,N)
    const float* __restrict__ Cim,      // (H,1,N)
    const float* __restrict__ Dv,       // (H,)
    float* __restrict__ K,              // (H,L)
    int L)
{
    const int h   = blockIdx.x;
    const int tid = threadIdx.x;

    __shared__ float2 s_a[NSTATE];     // (are, aim) = dtA
    __shared__ float2 s_step[NSTATE];  // exp(dtA)
    __shared__ float2 s_cb[NSTATE];    // CB

    if (tid < NSTATE) {
        const int n   = tid;
        const int idx = h * NSTATE + n;
        const float dt  = expf(log_dt[h]);
        const float lre = Lre[idx];
        const float lim = Lim[idx];
        const float are = dt * lre;
        const float aim = dt * lim;

        // Stable complex expm1: exp(are+i*aim) - 1
        float sy, cy;
        sincosf(aim, &sy, &cy);
        const float sh    = sinf(0.5f * aim);
        const float em_re = expm1f(are) * cy - 2.0f * sh * sh;
        const float em_im = expf(are) * sy;

        // B_bar = em / Lambda * B
        const float inv_d = 1.0f / (lre * lre + lim * lim);
        const float b     = Bv[idx];
        const float bb_re = (em_re * lre + em_im * lim) * inv_d * b;
        const float bb_im = (em_im * lre - em_re * lim) * inv_d * b;

        // CB = (Cre + i*Cim) * B_bar
        const float cre = Cre[idx];
        const float cim = Cim[idx];
        s_cb[n]   = make_float2(cre * bb_re - cim * bb_im,
                                cre * bb_im + cim * bb_re);
        s_a[n]    = make_float2(are, aim);
        // step = exp(dtA) = expm1(dtA) + 1
        s_step[n] = make_float2(em_re + 1.0f, em_im);
    }
    __syncthreads();

    const float Dh = Dv[h];

    for (int l0 = tid * TCHUNK; l0 < L; l0 += blockDim.x * TCHUNK) {
        const float fl = (float)l0;
        float acc[TCHUNK];
        #pragma unroll
        for (int t = 0; t < TCHUNK; ++t) acc[t] = 0.0f;

        #pragma unroll 4
        for (int n = 0; n < NSTATE; ++n) {
            const float2 a  = s_a[n];
            const float2 st = s_step[n];
            const float2 cb = s_cb[n];

            // z0 = exp(dtA * l0)
            const float mag = __expf(a.x * fl);
            float s, c;
            __sincosf(a.y * fl, &s, &c);
            // w = CB * z0  (fold magnitude into both parts)
            float wr = mag * (cb.x * c - cb.y * s);
            float wi = mag * (cb.x * s + cb.y * c);

            #pragma unroll
            for (int t = 0; t < TCHUNK; ++t) {
                acc[t] += wr;
                if (t < TCHUNK - 1) {
                    const float nr = wr * st.x - wi * st.y;
                    wi = wr * st.y + wi * st.x;
                    wr = nr;
                }
            }
        }

        float4 outv;
        outv.x = 2.0f * acc[0];
        outv.y = 2.0f * acc[1];
        outv.z = 2.0f * acc[2];
        outv.w = 2.0f * acc[3];
        if (l0 == 0) outv.x += Dh;
        *(float4*)(K + h * L + l0) = outv;
    }
}

extern "C" void kernel_launch(void* const* d_in, const int* in_sizes, int n_in,
                              void* d_out, int out_size, void* d_ws, size_t ws_size,
                              hipStream_t stream) {
    const float* log_dt = (const float*)d_in[0];
    const float* Lre    = (const float*)d_in[1];
    const float* Lim    = (const float*)d_in[2];
    const float* B      = (const float*)d_in[3];
    const float* Cre    = (const float*)d_in[4];
    const float* Cim    = (const float*)d_in[5];
    const float* D      = (const float*)d_in[6];
    const int H = in_sizes[0];
    const int L = out_size / H;
    float* K = (float*)d_out;

    ssk_diag_kernel<<<H, 256, 0, stream>>>(log_dt, Lre, Lim, B, Cre, Cim, D, K, L);
}

// Round 3
// 77.480 us; speedup vs baseline: 1.2620x; 1.0816x over previous
//
#include <hip/hip_runtime.h>
#include <math.h>

// S4D SSM kernel materialization:
//   K[h,l] = 2 * Re( sum_n CB[h,n] * exp(dtA[h,n] * l) ) + D[h]*(l==0)
//
// R3 strategy:
//  - T=8 l-values per thread (block=128, one h per block, one chunk/thread):
//    trans ops amortized 8x (3 per (n,thread)), LDS reads halved vs T=4.
//  - Two states (n, n+1) processed as <2 x float> SoA vectors so the rotation
//    recurrence and accumulate compile to v_pk_fma_f32 / v_pk_add_f32
//    (packed fp32 = the only path to the 157 TF vector fp32 rate).

#define NSTATE 64
#define TCHUNK 8

typedef float v2f __attribute__((ext_vector_type(2)));

__global__ __launch_bounds__(128) void ssk_diag_kernel(
    const float* __restrict__ log_dt,   // (H,)
    const float* __restrict__ Lre,      // (H,N)
    const float* __restrict__ Lim,      // (H,N)
    const float* __restrict__ Bv,       // (H,N,1)
    const float* __restrict__ Cre,      // (H,1,N)
    const float* __restrict__ Cim,      // (H,1,N)
    const float* __restrict__ Dv,       // (H,)
    float* __restrict__ K,              // (H,L)
    int L)
{
    const int h   = blockIdx.x;
    const int tid = threadIdx.x;

    // SoA so even-n pairs are contiguous for v2f loads
    __shared__ float s_are[NSTATE], s_aim[NSTATE];
    __shared__ float s_str[NSTATE], s_sti[NSTATE];   // step = exp(dtA)
    __shared__ float s_cbr[NSTATE], s_cbi[NSTATE];   // CB

    if (tid < NSTATE) {
        const int n   = tid;
        const int idx = h * NSTATE + n;
        const float dt  = expf(log_dt[h]);
        const float lre = Lre[idx];
        const float lim = Lim[idx];
        const float are = dt * lre;
        const float aim = dt * lim;

        // Stable complex expm1: exp(are+i*aim) - 1
        float sy, cy;
        sincosf(aim, &sy, &cy);
        const float sh    = sinf(0.5f * aim);
        const float em_re = expm1f(are) * cy - 2.0f * sh * sh;
        const float em_im = expf(are) * sy;

        // B_bar = em / Lambda * B
        const float inv_d = 1.0f / (lre * lre + lim * lim);
        const float b     = Bv[idx];
        const float bb_re = (em_re * lre + em_im * lim) * inv_d * b;
        const float bb_im = (em_im * lre - em_re * lim) * inv_d * b;

        // CB = (Cre + i*Cim) * B_bar
        const float cre = Cre[idx];
        const float cim = Cim[idx];
        s_cbr[n] = cre * bb_re - cim * bb_im;
        s_cbi[n] = cre * bb_im + cim * bb_re;
        s_are[n] = are;
        s_aim[n] = aim;
        s_str[n] = em_re + 1.0f;   // exp(dtA) = expm1(dtA) + 1
        s_sti[n] = em_im;
    }
    __syncthreads();

    const float Dh = Dv[h];

    for (int l0 = tid * TCHUNK; l0 < L; l0 += blockDim.x * TCHUNK) {
        const float fl = (float)l0;
        v2f acc[TCHUNK];
        #pragma unroll
        for (int t = 0; t < TCHUNK; ++t) acc[t] = (v2f){0.0f, 0.0f};

        #pragma unroll 2
        for (int n = 0; n < NSTATE; n += 2) {
            const v2f ar  = *(const v2f*)&s_are[n];
            const v2f ai  = *(const v2f*)&s_aim[n];
            const v2f str_= *(const v2f*)&s_str[n];
            const v2f sti = *(const v2f*)&s_sti[n];
            const v2f cbr = *(const v2f*)&s_cbr[n];
            const v2f cbi = *(const v2f*)&s_cbi[n];

            // z0 = exp(dtA * l0): scalar transcendentals per component
            const v2f argr = ar * fl;
            const v2f argi = ai * fl;
            const float m0 = __expf(argr.x);
            const float m1 = __expf(argr.y);
            float s0, c0, s1, c1;
            __sincosf(argi.x, &s0, &c0);
            __sincosf(argi.y, &s1, &c1);
            const v2f zr = {m0 * c0, m1 * c1};
            const v2f zi = {m0 * s0, m1 * s1};

            // w = CB * z0
            v2f wr = cbr * zr - cbi * zi;
            v2f wi = cbr * zi + cbi * zr;

            #pragma unroll
            for (int t = 0; t < TCHUNK; ++t) {
                acc[t] += wr;
                if (t < TCHUNK - 1) {
                    const v2f nr = wr * str_ - wi * sti;
                    wi = wr * sti + wi * str_;
                    wr = nr;
                }
            }
        }

        float4 o0, o1;
        o0.x = 2.0f * (acc[0].x + acc[0].y);
        o0.y = 2.0f * (acc[1].x + acc[1].y);
        o0.z = 2.0f * (acc[2].x + acc[2].y);
        o0.w = 2.0f * (acc[3].x + acc[3].y);
        o1.x = 2.0f * (acc[4].x + acc[4].y);
        o1.y = 2.0f * (acc[5].x + acc[5].y);
        o1.z = 2.0f * (acc[6].x + acc[6].y);
        o1.w = 2.0f * (acc[7].x + acc[7].y);
        if (l0 == 0) o0.x += Dh;
        *(float4*)(K + h * L + l0)     = o0;
        *(float4*)(K + h * L + l0 + 4) = o1;
    }
}

extern "C" void kernel_launch(void* const* d_in, const int* in_sizes, int n_in,
                              void* d_out, int out_size, void* d_ws, size_t ws_size,
                              hipStream_t stream) {
    const float* log_dt = (const float*)d_in[0];
    const float* Lre    = (const float*)d_in[1];
    const float* Lim    = (const float*)d_in[2];
    const float* B      = (const float*)d_in[3];
    const float* Cre    = (const float*)d_in[4];
    const float* Cim    = (const float*)d_in[5];
    const float* D      = (const float*)d_in[6];
    const int H = in_sizes[0];
    const int L = out_size / H;
    float* K = (float*)d_out;

    ssk_diag_kernel<<<H, 128, 0, stream>>>(log_dt, Lre, Lim, B, Cre, Cim, D, K, L);
}

// Round 4
// 75.736 us; speedup vs baseline: 1.2911x; 1.0230x over previous
//
#include <hip/hip_runtime.h>
#include <math.h>

// S4D SSM kernel materialization:
//   K[h,l] = 2 * Re( sum_n CB[h,n] * exp(dtA[h,n] * l) ) + D[h]*(l==0)
//
// R4 strategy (assumes L = 1024, N = 64 per the problem spec):
//  - block = 256 (4 waves), one h per block. Wave w owns states [16w,16w+16)
//    (8 even pairs, processed as <2 x float> SoA). Each lane owns a chunk of
//    T=16 consecutive l values. z0 = exp(dtA*l0) evaluated once per
//    (pair, lane) with fast trans; then a 15-step complex-rotation recurrence
//    (step = exp(dtA), precomputed) generates the chunk — no trans inside.
//  - T=16 halves trans/setup cost vs R3 while *raising* occupancy to
//    4 waves/SIMD (vs R3's 2) because the state split keeps 256-thr blocks.
//  - Cross-wave reduction via LDS partials in interleaved layout
//    pos(l) = (l&15)*64 + (l>>4): the 16 partial writes per thread are
//    lane-consecutive (conflict-free); the one-shot reduction reads are
//    4-way conflicted (negligible, ~150 cyc).
//  - Final *2 folded into CB at setup.

#define NSTATE 64
#define TCHUNK 16

typedef float v2f __attribute__((ext_vector_type(2)));

__global__ __launch_bounds__(256) void ssk_diag_kernel(
    const float* __restrict__ log_dt,   // (H,)
    const float* __restrict__ Lre,      // (H,N)
    const float* __restrict__ Lim,      // (H,N)
    const float* __restrict__ Bv,       // (H,N,1)
    const float* __restrict__ Cre,      // (H,1,N)
    const float* __restrict__ Cim,      // (H,1,N)
    const float* __restrict__ Dv,       // (H,)
    float* __restrict__ K,              // (H,L)
    int L)
{
    const int h   = blockIdx.x;
    const int tid = threadIdx.x;

    // SoA so even-n pairs are contiguous for v2f loads
    __shared__ float s_are[NSTATE], s_aim[NSTATE];
    __shared__ float s_str[NSTATE], s_sti[NSTATE];   // step = exp(dtA)
    __shared__ float s_cbr[NSTATE], s_cbi[NSTATE];   // 2*CB
    __shared__ float s_part[4 * 1024];               // per-wave partials, 16 KB

    if (tid < NSTATE) {
        const int n   = tid;
        const int idx = h * NSTATE + n;
        const float dt  = expf(log_dt[h]);
        const float lre = Lre[idx];
        const float lim = Lim[idx];
        const float are = dt * lre;
        const float aim = dt * lim;

        // Stable complex expm1: exp(are+i*aim) - 1
        float sy, cy;
        sincosf(aim, &sy, &cy);
        const float sh    = sinf(0.5f * aim);
        const float em_re = expm1f(are) * cy - 2.0f * sh * sh;
        const float em_im = expf(are) * sy;

        // B_bar = em / Lambda * B
        const float inv_d = 1.0f / (lre * lre + lim * lim);
        const float b     = Bv[idx];
        const float bb_re = (em_re * lre + em_im * lim) * inv_d * b;
        const float bb_im = (em_im * lre - em_re * lim) * inv_d * b;

        // 2*CB = 2 * (Cre + i*Cim) * B_bar   (fold the final *2 in here)
        const float cre = Cre[idx];
        const float cim = Cim[idx];
        s_cbr[n] = 2.0f * (cre * bb_re - cim * bb_im);
        s_cbi[n] = 2.0f * (cre * bb_im + cim * bb_re);
        s_are[n] = are;
        s_aim[n] = aim;
        s_str[n] = em_re + 1.0f;   // exp(dtA) = expm1(dtA) + 1
        s_sti[n] = em_im;
    }
    __syncthreads();

    const int wave = tid >> 6;
    const int lane = tid & 63;
    const int l0   = lane * TCHUNK;
    const float fl = (float)l0;

    v2f acc[TCHUNK];
    #pragma unroll
    for (int t = 0; t < TCHUNK; ++t) acc[t] = (v2f){0.0f, 0.0f};

    const int nb = wave * 16;   // this wave's 16 states = 8 even pairs
    #pragma unroll
    for (int p = 0; p < 8; ++p) {
        const int n = nb + 2 * p;
        const v2f ar  = *(const v2f*)&s_are[n];
        const v2f ai  = *(const v2f*)&s_aim[n];
        const v2f str_= *(const v2f*)&s_str[n];
        const v2f sti = *(const v2f*)&s_sti[n];
        const v2f cbr = *(const v2f*)&s_cbr[n];
        const v2f cbi = *(const v2f*)&s_cbi[n];

        // z0 = exp(dtA * l0)
        const v2f argr = ar * fl;
        const v2f argi = ai * fl;
        const float m0 = __expf(argr.x);
        const float m1 = __expf(argr.y);
        float s0, c0, s1, c1;
        __sincosf(argi.x, &s0, &c0);
        __sincosf(argi.y, &s1, &c1);
        const v2f zr = {m0 * c0, m1 * c1};
        const v2f zi = {m0 * s0, m1 * s1};

        // w = (2*CB) * z0
        v2f wr = cbr * zr - cbi * zi;
        v2f wi = cbr * zi + cbi * zr;

        #pragma unroll
        for (int t = 0; t < TCHUNK; ++t) {
            acc[t] += wr;
            if (t < TCHUNK - 1) {
                const v2f nr = wr * str_ - wi * sti;
                wi = wr * sti + wi * str_;
                wr = nr;
            }
        }
    }

    // Write per-wave partials, interleaved: pos(l) = (l&15)*64 + (l>>4).
    // For this thread, l = l0 + t -> pos = t*64 + lane (lane-consecutive).
    {
        float* base = &s_part[wave * 1024];
        #pragma unroll
        for (int t = 0; t < TCHUNK; ++t)
            base[t * 64 + lane] = acc[t].x + acc[t].y;
    }
    __syncthreads();

    // Reduce 4 waves' partials; thread tid produces l = 4*tid .. 4*tid+3.
    const int sub = tid & 3;
    const int blk = tid >> 2;
    float4 o;
    float* op = &o.x;
    #pragma unroll
    for (int k = 0; k < 4; ++k) {
        const int pos = (4 * sub + k) * 64 + blk;
        op[k] = s_part[pos] + s_part[1024 + pos] +
                s_part[2048 + pos] + s_part[3072 + pos];
    }
    if (tid == 0) o.x += Dv[h];
    *(float4*)(K + h * L + tid * 4) = o;
}

extern "C" void kernel_launch(void* const* d_in, const int* in_sizes, int n_in,
                              void* d_out, int out_size, void* d_ws, size_t ws_size,
                              hipStream_t stream) {
    const float* log_dt = (const float*)d_in[0];
    const float* Lre    = (const float*)d_in[1];
    const float* Lim    = (const float*)d_in[2];
    const float* B      = (const float*)d_in[3];
    const float* Cre    = (const float*)d_in[4];
    const float* Cim    = (const float*)d_in[5];
    const float* D      = (const float*)d_in[6];
    const int H = in_sizes[0];
    const int L = out_size / H;   // 1024 per problem spec (kernel assumes this)
    float* K = (float*)d_out;

    ssk_diag_kernel<<<H, 256, 0, stream>>>(log_dt, Lre, Lim, B, Cre, Cim, D, K, L);
}